// Round 8
// baseline (44.751 us; speedup 1.0000x reference)
//
#include <hip/hip_runtime.h>
#include <hip/hip_bf16.h>
#include <math.h>

#define N_ROWS 8192
#define N_HALF 4096
#define D 128
#define IT_ROWS 64
#define IBLKS (N_ROWS / IT_ROWS)        // 128 i-tiles of 64 rows
#define SEGS 8
#define SEGCOLS (N_ROWS / SEGS)         // 1024 cols per block
#define HALVES (SEGCOLS / 64)           // 16 halves of 64 cols
// scale = sqrt(2 * log2(e)): zb_i . zb_j = 2*log2(e)*cos -> exp2(dot) = exp(2*cos)
#define ZSCALE 1.6986437717f
#define LN2 0.69314718056f

typedef __attribute__((ext_vector_type(8))) short bfrag;   // 8 bf16 = 4 VGPR
typedef __attribute__((ext_vector_type(4))) float f32x4;

__device__ __forceinline__ float fast_exp2(float x) {
#if __has_builtin(__builtin_amdgcn_exp2f)
    return __builtin_amdgcn_exp2f(x);
#else
    return exp2f(x);
#endif
}

// ---------------- kernel 1: normalize rows; emit scaled bf16 z ----------------
__global__ __launch_bounds__(256) void normalize_kernel(
    const float* __restrict__ p1, const float* __restrict__ p2,
    ushort* __restrict__ zb)
{
    const int row = blockIdx.x * 4 + (threadIdx.x >> 6);
    const int lane = threadIdx.x & 63;
    const float* src = (row < N_HALF) ? (p1 + (size_t)row * D)
                                      : (p2 + (size_t)(row - N_HALF) * D);
    float2 v = ((const float2*)src)[lane];
    float ss = v.x * v.x + v.y * v.y;
    #pragma unroll
    for (int m = 1; m < 64; m <<= 1) ss += __shfl_xor(ss, m);
    float inv = ZSCALE / fmaxf(sqrtf(ss), 1e-12f);
    __hip_bfloat16 h0 = __float2bfloat16(v.x * inv);
    __hip_bfloat16 h1 = __float2bfloat16(v.y * inv);
    ushort2 u; u.x = *(ushort*)&h0; u.y = *(ushort*)&h1;
    ((ushort2*)(zb + (size_t)row * D))[lane] = u;
}

// ---------------- kernel 2: barrier-free per-wave DMA pipeline + MFMA Gram ----------------
// Each wave stages ITS OWN 16-col slice of each 64x128 half (wave-private LDS
// region) and reads only that region back -> no cross-wave hazard, no barriers.
// Counted vmcnt(4) keeps next half's 4 DMAs in flight while current is consumed.
// LDS slot s (16B): j-col r = s>>4, k-chunk c16 = (s&15)^(r&7) (rule #21 pair).
__global__ __launch_bounds__(256, 3) void simloss_mfma(
    const ushort* __restrict__ zb, float* __restrict__ partial,
    float* __restrict__ posv)
{
    __shared__ ushort Bs[2][64 * 128];   // 2 x 16 KB
    __shared__ float red[IT_ROWS][4];
    const int t = threadIdx.x;
    const int w = t >> 6;                // wave 0..3 -> 16-col slice of each half
    const int l = t & 63;
    const int l15 = l & 15, lh = l >> 4;
    const int bi = blockIdx.x & (IBLKS - 1);
    const int seg = blockIdx.x >> 7;
    const int iBase = bi * IT_ROWS;      // 64-aligned
    const int segBase = seg * SEGCOLS;
    const int pBase = iBase ^ N_HALF;    // partner tile base (64-aligned)

// stage this wave's quarter of one 64x128 half: 4 DMA issues, wave-linear LDS,
// per-lane inverse-swizzled global source.
#define STAGE(buf, jB)                                                          \
    {                                                                           \
        _Pragma("unroll")                                                       \
        for (int i = 0; i < 4; ++i) {                                           \
            const int s = w * 256 + i * 64 + l;                                 \
            const int r = s >> 4;                                               \
            const int c = (s & 15) ^ (r & 7);                                   \
            const ushort* g = zb + (size_t)((jB) + r) * D + c * 8;              \
            ushort* lp = (buf) + (size_t)s * 8;                                 \
            __builtin_amdgcn_global_load_lds(                                   \
                (const __attribute__((address_space(1))) unsigned int*)g,       \
                (__attribute__((address_space(3))) unsigned int*)lp, 16, 0, 0); \
        }                                                                       \
    }

    // A tile (64 rows x 128 k) in registers (L2-resident source)
    bfrag a[4][4];
    #pragma unroll
    for (int m = 0; m < 4; ++m) {
        const ushort* rp = zb + (size_t)(iBase + m * 16 + l15) * D;
        #pragma unroll
        for (int ks = 0; ks < 4; ++ks)
            a[m][ks] = *(const bfrag*)(rp + ks * 32 + lh * 8);
    }

    float rs[4][4];
    #pragma unroll
    for (int m = 0; m < 4; ++m)
        #pragma unroll
        for (int r = 0; r < 4; ++r) rs[m][r] = 0.0f;

    STAGE(&Bs[0][0], segBase);           // prologue: half 0 in flight

    const int cB = w * 16 + l15;         // this lane's col within each half

    #pragma unroll 1
    for (int h = 0; h < HALVES; ++h) {
        const int jBase = segBase + h * 64;
        const ushort* bufc = &Bs[h & 1][0];

        if (h + 1 < HALVES) {
            STAGE(&Bs[(h + 1) & 1][0], jBase + 64);       // next half in flight
            asm volatile("s_waitcnt vmcnt(4)" ::: "memory");  // current half landed
        } else {
            asm volatile("s_waitcnt vmcnt(0)" ::: "memory");
        }

        bfrag b[4];
        #pragma unroll
        for (int ks = 0; ks < 4; ++ks) {
            const int k16 = ks * 4 + lh;
            const int slot = cB * 16 + (k16 ^ (cB & 7));
            b[ks] = *(const bfrag*)(bufc + slot * 8);
        }

        f32x4 c[4];
        #pragma unroll
        for (int m = 0; m < 4; ++m) { f32x4 z4 = {0.f, 0.f, 0.f, 0.f}; c[m] = z4; }
        #pragma unroll
        for (int ks = 0; ks < 4; ++ks)
            #pragma unroll
            for (int m = 0; m < 4; ++m)
                c[m] = __builtin_amdgcn_mfma_f32_16x16x32_bf16(a[m][ks], b[ks], c[m], 0, 0, 0);

        if (jBase == iBase) {            // rare: half covers self-diagonal
            #pragma unroll
            for (int m = 0; m < 4; ++m)
                #pragma unroll
                for (int r = 0; r < 4; ++r) {
                    const int rowLocal = m * 16 + lh * 4 + r;
                    float e = fast_exp2(c[m][r]);
                    rs[m][r] += (rowLocal == cB) ? 0.0f : e;
                }
        } else {                         // hot path
            #pragma unroll
            for (int m = 0; m < 4; ++m)
                #pragma unroll
                for (int r = 0; r < 4; ++r)
                    rs[m][r] += fast_exp2(c[m][r]);
        }
        if (jBase == pBase) {            // rare: half covers partner diagonal
            #pragma unroll
            for (int m = 0; m < 4; ++m)
                #pragma unroll
                for (int r = 0; r < 4; ++r) {
                    const int rowLocal = m * 16 + lh * 4 + r;
                    if (rowLocal == cB)
                        posv[iBase + rowLocal] = c[m][r] * LN2;   // = 2*cos
                }
        }
    }
#undef STAGE

    // reduce rs over the 16 cols held across l15 lanes
    #pragma unroll
    for (int m = 0; m < 4; ++m)
        #pragma unroll
        for (int r = 0; r < 4; ++r) {
            float v = rs[m][r];
            v += __shfl_xor(v, 1); v += __shfl_xor(v, 2);
            v += __shfl_xor(v, 4); v += __shfl_xor(v, 8);
            rs[m][r] = v;
        }
    if (l15 == 0) {
        #pragma unroll
        for (int m = 0; m < 4; ++m)
            #pragma unroll
            for (int r = 0; r < 4; ++r)
                red[m * 16 + lh * 4 + r][w] = rs[m][r];
    }
    __syncthreads();
    if (t < IT_ROWS) {
        float v = red[t][0] + red[t][1] + red[t][2] + red[t][3];
        partial[(size_t)seg * N_ROWS + iBase + t] = v;
    }
}

// ---------------- kernel 3: fused per-row loss + deterministic global reduce ----------------
__global__ __launch_bounds__(1024) void loss_reduce(
    const float* __restrict__ partial, const float* __restrict__ posv,
    float* __restrict__ out)
{
    const int t = threadIdx.x;
    float loss = 0.0f;
    #pragma unroll
    for (int k = 0; k < N_ROWS / 1024; ++k) {
        const int row = k * 1024 + t;
        float denom = 0.0f;
        #pragma unroll
        for (int s = 0; s < SEGS; ++s) denom += partial[(size_t)s * N_ROWS + row];
        loss += logf(denom) - posv[row];
    }
    #pragma unroll
    for (int m = 1; m < 64; m <<= 1) loss += __shfl_xor(loss, m);
    __shared__ float wsum[16];
    if ((t & 63) == 0) wsum[t >> 6] = loss;
    __syncthreads();
    if (t == 0) {
        float s = 0.0f;
        #pragma unroll
        for (int i = 0; i < 16; ++i) s += wsum[i];   // fixed order: deterministic
        out[0] = s * (1.0f / (float)N_ROWS);
    }
}

extern "C" void kernel_launch(void* const* d_in, const int* in_sizes, int n_in,
                              void* d_out, int out_size, void* d_ws, size_t ws_size,
                              hipStream_t stream) {
    const float* proj1 = (const float*)d_in[0];
    const float* proj2 = (const float*)d_in[1];
    float* out = (float*)d_out;

    char* ws = (char*)d_ws;
    ushort* zb      = (ushort*)ws;                                      // 2 MB
    float*  partial = (float*)(ws + (size_t)2 * 1024 * 1024);           // 256 KB
    float*  posv    = (float*)(ws + (size_t)2 * 1024 * 1024 + 512 * 1024);   // 32 KB

    normalize_kernel<<<N_ROWS / 4, 256, 0, stream>>>(proj1, proj2, zb);
    simloss_mfma<<<IBLKS * SEGS, 256, 0, stream>>>(zb, partial, posv);
    loss_reduce<<<1, 1024, 0, stream>>>(partial, posv, out);
}

// Round 9
// 41.408 us; speedup vs baseline: 1.0807x; 1.0807x over previous
//
#include <hip/hip_runtime.h>
#include <hip/hip_bf16.h>
#include <math.h>

#define N_ROWS 8192
#define N_HALF 4096
#define D 128
#define SEGS 8
#define IBLKS (N_ROWS / 128)            // 64 i-tiles of 128 rows
#define SEGCOLS (N_ROWS / SEGS)         // 1024 cols per block
#define HALVES (SEGCOLS / 64)           // 16 halves of 64 cols
// scale = sqrt(2 * log2(e)): zb_i . zb_j = 2*log2(e)*cos -> exp2(dot) = exp(2*cos)
#define ZSCALE 1.6986437717f
#define LN2 0.69314718056f

typedef __attribute__((ext_vector_type(8))) short bfrag;   // 8 bf16 = 4 VGPR
typedef __attribute__((ext_vector_type(4))) float f32x4;

__device__ __forceinline__ float fast_exp2(float x) {
#if __has_builtin(__builtin_amdgcn_exp2f)
    return __builtin_amdgcn_exp2f(x);
#else
    return exp2f(x);
#endif
}

// ---------------- kernel 1: normalize rows; emit scaled bf16 z ----------------
__global__ __launch_bounds__(256) void normalize_kernel(
    const float* __restrict__ p1, const float* __restrict__ p2,
    ushort* __restrict__ zb)
{
    const int row = blockIdx.x * 4 + (threadIdx.x >> 6);
    const int lane = threadIdx.x & 63;
    const float* src = (row < N_HALF) ? (p1 + (size_t)row * D)
                                      : (p2 + (size_t)(row - N_HALF) * D);
    float2 v = ((const float2*)src)[lane];
    float ss = v.x * v.x + v.y * v.y;
    #pragma unroll
    for (int m = 1; m < 64; m <<= 1) ss += __shfl_xor(ss, m);
    float inv = ZSCALE / fmaxf(sqrtf(ss), 1e-12f);
    __hip_bfloat16 h0 = __float2bfloat16(v.x * inv);
    __hip_bfloat16 h1 = __float2bfloat16(v.y * inv);
    ushort2 u; u.x = *(ushort*)&h0; u.y = *(ushort*)&h1;
    ((ushort2*)(zb + (size_t)row * D))[lane] = u;
}

// ---------------- kernel 2: barrier-free dbuf DMA + MFMA Gram (reuse-8 tile) ----------------
// Each wave stages ITS OWN 16-col slice of each 64x128 half into a wave-private
// LDS region and reads only that region -> no cross-wave hazard, NO barriers.
// Counted vmcnt(4): next half's 4 DMAs stay in flight while current is consumed.
// LDS slot s (16B): j-col r = s>>4, k-chunk c16 = (s&15)^(r&7) (rule #21 pair).
__global__ __launch_bounds__(256, 2) void simloss_mfma(
    const ushort* __restrict__ zb, float* __restrict__ partial,
    float* __restrict__ posv)
{
    __shared__ ushort Bs[2][64 * 128];   // 2 x 16 KB
    __shared__ float red[128][4];
    const int t = threadIdx.x;
    const int w = t >> 6;                // wave 0..3 -> 16-col slice of each half
    const int l = t & 63;
    const int l15 = l & 15, lh = l >> 4;
    const int bi = blockIdx.x & (IBLKS - 1);
    const int seg = blockIdx.x >> 6;
    const int iBase = bi * 128;
    const int segBase = seg * SEGCOLS;
    const int pBase = iBase ^ N_HALF;    // partner tile base (128-aligned)

// stage this wave's quarter of one 64x128 half: 4 DMA issues, wave-linear LDS,
// per-lane inverse-swizzled global source.
#define STAGE(buf, jB)                                                          \
    {                                                                           \
        _Pragma("unroll")                                                       \
        for (int i = 0; i < 4; ++i) {                                           \
            const int s = w * 256 + i * 64 + l;                                 \
            const int r = s >> 4;                                               \
            const int c = (s & 15) ^ (r & 7);                                   \
            const ushort* g = zb + (size_t)((jB) + r) * D + c * 8;              \
            ushort* lp = (buf) + (size_t)s * 8;                                 \
            __builtin_amdgcn_global_load_lds(                                   \
                (const __attribute__((address_space(1))) unsigned int*)g,       \
                (__attribute__((address_space(3))) unsigned int*)lp, 16, 0, 0); \
        }                                                                       \
    }

    // A tile (128 rows x 128 k) in registers (L2-resident source)
    bfrag a[8][4];
    #pragma unroll
    for (int m = 0; m < 8; ++m) {
        const ushort* rp = zb + (size_t)(iBase + m * 16 + l15) * D;
        #pragma unroll
        for (int ks = 0; ks < 4; ++ks)
            a[m][ks] = *(const bfrag*)(rp + ks * 32 + lh * 8);
    }

    float rs[8][4];
    #pragma unroll
    for (int m = 0; m < 8; ++m)
        #pragma unroll
        for (int r = 0; r < 4; ++r) rs[m][r] = 0.0f;

    STAGE(&Bs[0][0], segBase);           // prologue: half 0 in flight

    const int cB = w * 16 + l15;         // this lane's col within each half

    #pragma unroll 1
    for (int h = 0; h < HALVES; ++h) {
        const int jBase = segBase + h * 64;
        const ushort* bufc = &Bs[h & 1][0];

        if (h + 1 < HALVES) {
            STAGE(&Bs[(h + 1) & 1][0], jBase + 64);          // next half in flight
            asm volatile("s_waitcnt vmcnt(4)" ::: "memory"); // current half landed
        } else {
            asm volatile("s_waitcnt vmcnt(0)" ::: "memory");
        }

        bfrag b[4];
        #pragma unroll
        for (int ks = 0; ks < 4; ++ks) {
            const int k16 = ks * 4 + lh;
            const int slot = cB * 16 + (k16 ^ (cB & 7));
            b[ks] = *(const bfrag*)(bufc + slot * 8);
        }

        f32x4 c[8];
        #pragma unroll
        for (int m = 0; m < 8; ++m) { f32x4 z4 = {0.f, 0.f, 0.f, 0.f}; c[m] = z4; }
        #pragma unroll
        for (int ks = 0; ks < 4; ++ks)
            #pragma unroll
            for (int m = 0; m < 8; ++m)
                c[m] = __builtin_amdgcn_mfma_f32_16x16x32_bf16(a[m][ks], b[ks], c[m], 0, 0, 0);

        if ((jBase & ~127) == iBase) {   // rare: half covers self-diagonal
            const int sOff = jBase - iBase;          // 0 or 64
            #pragma unroll
            for (int m = 0; m < 8; ++m)
                #pragma unroll
                for (int r = 0; r < 4; ++r) {
                    const int rowLocal = m * 16 + lh * 4 + r;
                    float e = fast_exp2(c[m][r]);
                    rs[m][r] += (rowLocal == sOff + cB) ? 0.0f : e;
                }
        } else {                         // hot path
            #pragma unroll
            for (int m = 0; m < 8; ++m)
                #pragma unroll
                for (int r = 0; r < 4; ++r)
                    rs[m][r] += fast_exp2(c[m][r]);
        }
        if ((jBase & ~127) == pBase) {   // rare: half covers partner diagonal
            const int pOff = jBase - pBase;          // 0 or 64
            #pragma unroll
            for (int m = 0; m < 8; ++m)
                #pragma unroll
                for (int r = 0; r < 4; ++r) {
                    const int rowLocal = m * 16 + lh * 4 + r;
                    if (rowLocal == pOff + cB)
                        posv[iBase + rowLocal] = c[m][r] * LN2;   // = 2*cos
                }
        }
    }
#undef STAGE

    // reduce rs over the 16 cols held across l15 lanes
    #pragma unroll
    for (int m = 0; m < 8; ++m)
        #pragma unroll
        for (int r = 0; r < 4; ++r) {
            float v = rs[m][r];
            v += __shfl_xor(v, 1); v += __shfl_xor(v, 2);
            v += __shfl_xor(v, 4); v += __shfl_xor(v, 8);
            rs[m][r] = v;
        }
    if (l15 == 0) {
        #pragma unroll
        for (int m = 0; m < 8; ++m)
            #pragma unroll
            for (int r = 0; r < 4; ++r)
                red[m * 16 + lh * 4 + r][w] = rs[m][r];
    }
    __syncthreads();                     // real cross-wave reduce: keep
    if (t < 128) {
        float v = red[t][0] + red[t][1] + red[t][2] + red[t][3];
        partial[(size_t)seg * N_ROWS + iBase + t] = v;
    }
}

// ---------------- kernel 3: fused per-row loss + deterministic global reduce ----------------
__global__ __launch_bounds__(1024) void loss_reduce(
    const float* __restrict__ partial, const float* __restrict__ posv,
    float* __restrict__ out)
{
    const int t = threadIdx.x;
    float loss = 0.0f;
    #pragma unroll
    for (int k = 0; k < N_ROWS / 1024; ++k) {
        const int row = k * 1024 + t;
        float denom = 0.0f;
        #pragma unroll
        for (int s = 0; s < SEGS; ++s) denom += partial[(size_t)s * N_ROWS + row];
        loss += logf(denom) - posv[row];
    }
    #pragma unroll
    for (int m = 1; m < 64; m <<= 1) loss += __shfl_xor(loss, m);
    __shared__ float wsum[16];
    if ((t & 63) == 0) wsum[t >> 6] = loss;
    __syncthreads();
    if (t == 0) {
        float s = 0.0f;
        #pragma unroll
        for (int i = 0; i < 16; ++i) s += wsum[i];   // fixed order: deterministic
        out[0] = s * (1.0f / (float)N_ROWS);
    }
}

extern "C" void kernel_launch(void* const* d_in, const int* in_sizes, int n_in,
                              void* d_out, int out_size, void* d_ws, size_t ws_size,
                              hipStream_t stream) {
    const float* proj1 = (const float*)d_in[0];
    const float* proj2 = (const float*)d_in[1];
    float* out = (float*)d_out;

    char* ws = (char*)d_ws;
    ushort* zb      = (ushort*)ws;                                      // 2 MB
    float*  partial = (float*)(ws + (size_t)2 * 1024 * 1024);           // 256 KB
    float*  posv    = (float*)(ws + (size_t)2 * 1024 * 1024 + 512 * 1024);   // 32 KB

    normalize_kernel<<<N_ROWS / 4, 256, 0, stream>>>(proj1, proj2, zb);
    simloss_mfma<<<IBLKS * SEGS, 256, 0, stream>>>(zb, partial, posv);
    loss_reduce<<<1, 1024, 0, stream>>>(partial, posv, out);
}